// Round 3
// baseline (345.237 us; speedup 1.0000x reference)
//
#include <hip/hip_runtime.h>
#include <math.h>

#define EPS 1e-5f
#define NPK (4096 * 128)   // 524288 pixels
#define PIXB 256           // pixels per block (2 tiles of 128)
#define PIXT (PIXB / 128)  // pixel-tile iterations per block

typedef __attribute__((ext_vector_type(8))) short bf16x8;   // 8 bf16 = 4 VGPRs
typedef __attribute__((ext_vector_type(4))) float f32x4;

__device__ __forceinline__ short f2bf(float f) {
    union { float f; unsigned u; } x; x.f = f;
    unsigned r = x.u + 0x7fffu + ((x.u >> 16) & 1u);   // round-to-nearest-even
    return (short)(r >> 16);
}

// ws layout (floats): A1[192] C1[64] C2[64] C3[128] | bf16: W2frag[4096] W3frag[8192]
// WNfrag = BN-folded weights pre-swizzled into MFMA B-fragment per-lane order:
//   frag[((nt*2+ks)*64 + lane)*8 + j] = Wfold[o = nt*16 + (lane&15)][i = ks*32 + (lane>>4)*8 + j]
#define WS_A1 0
#define WS_C1 192
#define WS_C2 256
#define WS_C3 320
#define WS_BF 448

__global__ void prep_kernel(
    const float* __restrict__ W1, const float* __restrict__ b1,
    const float* __restrict__ g1, const float* __restrict__ be1,
    const float* __restrict__ m1, const float* __restrict__ v1,
    const float* __restrict__ W2, const float* __restrict__ b2,
    const float* __restrict__ g2, const float* __restrict__ be2,
    const float* __restrict__ m2, const float* __restrict__ v2,
    const float* __restrict__ W3, const float* __restrict__ b3,
    const float* __restrict__ g3, const float* __restrict__ be3,
    const float* __restrict__ m3, const float* __restrict__ v3,
    float* __restrict__ ws)
{
    const int t = blockIdx.x * 256 + threadIdx.x;
    const int stride = gridDim.x * 256;
    if (t < 64) {
        float inv1 = g1[t] * rsqrtf(v1[t] + EPS);
        ws[WS_C1 + t] = b1[t] * inv1 + be1[t] - m1[t] * inv1;
        ws[WS_A1 + t * 3 + 0] = W1[t * 3 + 0] * inv1;
        ws[WS_A1 + t * 3 + 1] = W1[t * 3 + 1] * inv1;
        ws[WS_A1 + t * 3 + 2] = W1[t * 3 + 2] * inv1;
        float inv2 = g2[t] * rsqrtf(v2[t] + EPS);
        ws[WS_C2 + t] = b2[t] * inv2 + be2[t] - m2[t] * inv2;
    }
    if (t >= 128 && t < 256) {
        int o = t - 128;
        float inv3 = g3[o] * rsqrtf(v3[o] + EPS);
        ws[WS_C3 + o] = b3[o] * inv3 + be3[o] - m3[o] * inv3;
    }
    short* W2f = (short*)(ws + WS_BF);
    short* W3f = W2f + 64 * 64;
    for (int idx = t; idx < 64 * 64; idx += stride) {
        int j = idx & 7, lane = (idx >> 3) & 63, tile = idx >> 9;
        int nt = tile >> 1, ks = tile & 1;
        int o = nt * 16 + (lane & 15);
        int i = ks * 32 + (lane >> 4) * 8 + j;
        float inv = g2[o] * rsqrtf(v2[o] + EPS);
        W2f[idx] = f2bf(W2[o * 64 + i] * inv);
    }
    for (int idx = t; idx < 128 * 64; idx += stride) {
        int j = idx & 7, lane = (idx >> 3) & 63, tile = idx >> 9;
        int nt = tile >> 1, ks = tile & 1;
        int o = nt * 16 + (lane & 15);
        int i = ks * 32 + (lane >> 4) * 8 + j;
        float inv = g3[o] * rsqrtf(v3[o] + EPS);
        W3f[idx] = f2bf(W3[o * 64 + i] * inv);
    }
}

// One block = 256 threads = 4 waves, PIXB=256 pixels as PIXT=2 tiles of 128;
// within a tile, wave w owns pixels [32w, 32w+32) as TWO m-tiles of 16.
// M = pixels, N = channels => C/D layout gives each lane 4 CONSECUTIVE PIXELS
// of one channel => plain f32x4 stores (NO nontemporal: cost +31 us, prior
// session round 3).
// Fragment layouts (HW-verified): A[m=lane&15][k=quad*8+j]
//   B[k=quad*8+j][n=lane&15]   C/D: col=lane&15, row=quad*4+reg
//
// ROUND-5/6: pixel-tile loop (128 -> 256 px/block). Rationale: round-4 proved
// LDS/barriers are off the critical path; residual slack (~2.8x over the
// write roofline) is attributed to DRAM efficiency of 512-B-per-channel
// write bursts. 256 px/block doubles each channel's contiguous run to 1 KB,
// halves independent write streams, and amortizes the 12 KB weight-fragment
// reads 2x. h2 rows stay wave-private => still ZERO barriers.
// (Round-5 bench was an infra failure — container acquisition; resubmitted.)
__global__ __launch_bounds__(256) void pointnet_mfma(
    const float* __restrict__ x, const float* __restrict__ valid,
    const float* __restrict__ ws, float* __restrict__ out)
{
    __shared__ short h2[128 * 72];   // 18432 B, [pixel][ch] pad 72

    const int t = threadIdx.x;
    const int lane = t & 63;
    const int w = t >> 6;
    const int lanelo = lane & 15;
    const int quad = lane >> 4;

    const float* __restrict__ A1 = ws + WS_A1;
    const float* __restrict__ C1 = ws + WS_C1;
    const float* __restrict__ C2 = ws + WS_C2;
    const float* __restrict__ C3 = ws + WS_C3;
    const short* __restrict__ W2f = (const short*)(ws + WS_BF);
    const short* __restrict__ W3f = W2f + 64 * 64;

    for (int pt = 0; pt < PIXT; ++pt) {
        const int pbase = blockIdx.x * PIXB + pt * 128;

        // ---- Layer 1: 3 -> 64 fp32, fused straight into MFMA A-fragments ----
        // a[mt][ks][j] = relu(W1fold . x + C1) at pixel (w*32+mt*16+lanelo),
        // channel (ks*32+quad*8+j). No LDS, no barrier.
        bf16x8 a[2][2];
        {
            const int p0 = pbase + w * 32 + lanelo;        // mt=0 pixel
            const float x00 = x[p0];
            const float x01 = x[p0 + NPK];
            const float x02 = x[p0 + 2 * NPK];
            const float x10 = x[p0 + 16];                  // mt=1 pixel
            const float x11 = x[p0 + 16 + NPK];
            const float x12 = x[p0 + 16 + 2 * NPK];
#pragma unroll
            for (int ks = 0; ks < 2; ++ks)
#pragma unroll
                for (int j = 0; j < 8; ++j) {
                    const int ch = ks * 32 + quad * 8 + j;
                    const float wa = A1[ch * 3 + 0];
                    const float wb = A1[ch * 3 + 1];
                    const float wc = A1[ch * 3 + 2];
                    const float cc = C1[ch];
                    const float y0 = fmaf(wa, x00, fmaf(wb, x01, fmaf(wc, x02, cc)));
                    const float y1 = fmaf(wa, x10, fmaf(wb, x11, fmaf(wc, x12, cc)));
                    a[0][ks][j] = f2bf(fmaxf(y0, 0.0f));
                    a[1][ks][j] = f2bf(fmaxf(y1, 0.0f));
                }
        }

        // ---- Layer 2: 2 m-tiles x 4 n-tiles, K=64; A-frags already in regs ----
        // h2 rows [32w, 32w+32) are private to this wave: no __syncthreads,
        // and cross-pt reuse is ordered by in-wave lgkmcnt.
#pragma unroll
        for (int nt = 0; nt < 4; ++nt) {
            bf16x8 b0 = *(const bf16x8*)&W2f[((nt * 2 + 0) * 64 + lane) * 8];
            bf16x8 b1 = *(const bf16x8*)&W2f[((nt * 2 + 1) * 64 + lane) * 8];
            const float bias = C2[nt * 16 + lanelo];
#pragma unroll
            for (int mt = 0; mt < 2; ++mt) {
                f32x4 acc = {0.f, 0.f, 0.f, 0.f};
                acc = __builtin_amdgcn_mfma_f32_16x16x32_bf16(a[mt][0], b0, acc, 0, 0, 0);
                acc = __builtin_amdgcn_mfma_f32_16x16x32_bf16(a[mt][1], b1, acc, 0, 0, 0);
#pragma unroll
                for (int r = 0; r < 4; ++r)
                    h2[(w * 32 + mt * 16 + quad * 4 + r) * 72 + nt * 16 + lanelo] =
                        f2bf(fmaxf(acc[r] + bias, 0.0f));
            }
        }

        // ---- Layer 3: 2 m-tiles x 8 n-tiles, K=64; fused epilogue ----
        {
            bf16x8 a2[2][2];
#pragma unroll
            for (int mt = 0; mt < 2; ++mt)
#pragma unroll
                for (int ks = 0; ks < 2; ++ks)
                    a2[mt][ks] = *(const bf16x8*)&h2[(w * 32 + mt * 16 + lanelo) * 72 + ks * 32 + quad * 8];
            f32x4 v4[2];
            v4[0] = *(const f32x4*)&valid[pbase + w * 32 + quad * 4];
            v4[1] = *(const f32x4*)&valid[pbase + w * 32 + 16 + quad * 4];
#pragma unroll
            for (int nt = 0; nt < 8; ++nt) {
                bf16x8 b0 = *(const bf16x8*)&W3f[((nt * 2 + 0) * 64 + lane) * 8];
                bf16x8 b1 = *(const bf16x8*)&W3f[((nt * 2 + 1) * 64 + lane) * 8];
                const float bias = C3[nt * 16 + lanelo];
                const long chbase = (long)(nt * 16 + lanelo) * NPK;
#pragma unroll
                for (int mt = 0; mt < 2; ++mt) {
                    f32x4 acc = {0.f, 0.f, 0.f, 0.f};
                    acc = __builtin_amdgcn_mfma_f32_16x16x32_bf16(a2[mt][0], b0, acc, 0, 0, 0);
                    acc = __builtin_amdgcn_mfma_f32_16x16x32_bf16(a2[mt][1], b1, acc, 0, 0, 0);
                    f32x4 o;
#pragma unroll
                    for (int r = 0; r < 4; ++r)
                        o[r] = fmaxf(acc[r] + bias, 0.0f) * v4[mt][r];
                    *(f32x4*)&out[chbase + pbase + w * 32 + mt * 16 + quad * 4] = o;
                }
            }
        }
    }
}

extern "C" void kernel_launch(void* const* d_in, const int* in_sizes, int n_in,
                              void* d_out, int out_size, void* d_ws, size_t ws_size,
                              hipStream_t stream) {
    const float* x     = (const float*)d_in[0];
    const float* valid = (const float*)d_in[1];

    const float* W1 = (const float*)d_in[2];
    const float* b1 = (const float*)d_in[3];
    const float* g1 = (const float*)d_in[4];
    const float* be1 = (const float*)d_in[5];
    const float* m1 = (const float*)d_in[6];
    const float* v1 = (const float*)d_in[7];

    const float* W2 = (const float*)d_in[8];
    const float* b2 = (const float*)d_in[9];
    const float* g2 = (const float*)d_in[10];
    const float* be2 = (const float*)d_in[11];
    const float* m2 = (const float*)d_in[12];
    const float* v2 = (const float*)d_in[13];

    const float* W3 = (const float*)d_in[14];
    const float* b3 = (const float*)d_in[15];
    const float* g3 = (const float*)d_in[16];
    const float* be3 = (const float*)d_in[17];
    const float* m3 = (const float*)d_in[18];
    const float* v3 = (const float*)d_in[19];

    float* ws  = (float*)d_ws;
    float* out = (float*)d_out;

    prep_kernel<<<16, 256, 0, stream>>>(W1, b1, g1, be1, m1, v1,
                                        W2, b2, g2, be2, m2, v2,
                                        W3, b3, g3, be3, m3, v3, ws);

    pointnet_mfma<<<NPK / PIXB, 256, 0, stream>>>(x, valid, ws, out);
}

// Round 4
// 338.821 us; speedup vs baseline: 1.0189x; 1.0189x over previous
//
#include <hip/hip_runtime.h>
#include <math.h>

#define EPS 1e-5f
#define NPK (4096 * 128)   // 524288 pixels
#define PIXB 256           // pixels per block (2 tiles of 128)
#define PIXT (PIXB / 128)  // pixel-tile iterations per block
#define NXCD 8

typedef __attribute__((ext_vector_type(8))) short bf16x8;   // 8 bf16 = 4 VGPRs
typedef __attribute__((ext_vector_type(4))) float f32x4;

__device__ __forceinline__ short f2bf(float f) {
    union { float f; unsigned u; } x; x.f = f;
    unsigned r = x.u + 0x7fffu + ((x.u >> 16) & 1u);   // round-to-nearest-even
    return (short)(r >> 16);
}

// ws layout (floats): A1[192] C1[64] C2[64] C3[128] | bf16: W2frag[4096] W3frag[8192]
// WNfrag = BN-folded weights pre-swizzled into MFMA B-fragment per-lane order:
//   frag[((nt*2+ks)*64 + lane)*8 + j] = Wfold[o = nt*16 + (lane&15)][i = ks*32 + (lane>>4)*8 + j]
#define WS_A1 0
#define WS_C1 192
#define WS_C2 256
#define WS_C3 320
#define WS_BF 448

__global__ void prep_kernel(
    const float* __restrict__ W1, const float* __restrict__ b1,
    const float* __restrict__ g1, const float* __restrict__ be1,
    const float* __restrict__ m1, const float* __restrict__ v1,
    const float* __restrict__ W2, const float* __restrict__ b2,
    const float* __restrict__ g2, const float* __restrict__ be2,
    const float* __restrict__ m2, const float* __restrict__ v2,
    const float* __restrict__ W3, const float* __restrict__ b3,
    const float* __restrict__ g3, const float* __restrict__ be3,
    const float* __restrict__ m3, const float* __restrict__ v3,
    float* __restrict__ ws)
{
    const int t = blockIdx.x * 256 + threadIdx.x;
    const int stride = gridDim.x * 256;
    if (t < 64) {
        float inv1 = g1[t] * rsqrtf(v1[t] + EPS);
        ws[WS_C1 + t] = b1[t] * inv1 + be1[t] - m1[t] * inv1;
        ws[WS_A1 + t * 3 + 0] = W1[t * 3 + 0] * inv1;
        ws[WS_A1 + t * 3 + 1] = W1[t * 3 + 1] * inv1;
        ws[WS_A1 + t * 3 + 2] = W1[t * 3 + 2] * inv1;
        float inv2 = g2[t] * rsqrtf(v2[t] + EPS);
        ws[WS_C2 + t] = b2[t] * inv2 + be2[t] - m2[t] * inv2;
    }
    if (t >= 128 && t < 256) {
        int o = t - 128;
        float inv3 = g3[o] * rsqrtf(v3[o] + EPS);
        ws[WS_C3 + o] = b3[o] * inv3 + be3[o] - m3[o] * inv3;
    }
    short* W2f = (short*)(ws + WS_BF);
    short* W3f = W2f + 64 * 64;
    for (int idx = t; idx < 64 * 64; idx += stride) {
        int j = idx & 7, lane = (idx >> 3) & 63, tile = idx >> 9;
        int nt = tile >> 1, ks = tile & 1;
        int o = nt * 16 + (lane & 15);
        int i = ks * 32 + (lane >> 4) * 8 + j;
        float inv = g2[o] * rsqrtf(v2[o] + EPS);
        W2f[idx] = f2bf(W2[o * 64 + i] * inv);
    }
    for (int idx = t; idx < 128 * 64; idx += stride) {
        int j = idx & 7, lane = (idx >> 3) & 63, tile = idx >> 9;
        int nt = tile >> 1, ks = tile & 1;
        int o = nt * 16 + (lane & 15);
        int i = ks * 32 + (lane >> 4) * 8 + j;
        float inv = g3[o] * rsqrtf(v3[o] + EPS);
        W3f[idx] = f2bf(W3[o * 64 + i] * inv);
    }
}

// One block = 256 threads = 4 waves, PIXB=256 pixels as PIXT=2 tiles of 128;
// within a tile, wave w owns pixels [32w, 32w+32) as TWO m-tiles of 16.
// M = pixels, N = channels => C/D layout gives each lane 4 CONSECUTIVE PIXELS
// of one channel => plain f32x4 stores (NO nontemporal: cost +31 us — proof
// the write path is sensitive; L2 64B->128B line merging matters).
// Fragment layouts (HW-verified): A[m=lane&15][k=quad*8+j]
//   B[k=quad*8+j][n=lane&15]   C/D: col=lane&15, row=quad*4+reg
//
// ROUND-7: XCD-chunked blockIdx swizzle (T1, bijective: 2048 % 8 == 0).
// Default dispatch puts block b on XCD b%8, so each XCD's write stream per
// channel is 1-KB runs at 8-KB stride (8-way interleaved across XCDs).
// swz = (b%8)*(nwg/8) + b/8 gives each XCD ONE contiguous 65536-pixel span:
// per channel, a single sequential 256-KB stream per XCD — fill-like DRAM
// locality on both the out-write and x-read side. Single-variable change.
// Prior nulls: h1-LDS/barriers (r1), PIXB 128->256 (r3).
__global__ __launch_bounds__(256) void pointnet_mfma(
    const float* __restrict__ x, const float* __restrict__ valid,
    const float* __restrict__ ws, float* __restrict__ out)
{
    __shared__ short h2[128 * 72];   // 18432 B, [pixel][ch] pad 72

    const int t = threadIdx.x;
    const int lane = t & 63;
    const int w = t >> 6;
    const int lanelo = lane & 15;
    const int quad = lane >> 4;

    // XCD-chunked bijective swizzle: XCD k owns contiguous pixel span
    // [k * (NPK/8), (k+1) * (NPK/8)).
    const int bid = blockIdx.x;
    const int cpx = gridDim.x >> 3;               // 256 blocks per XCD chunk
    const int swz = (bid & (NXCD - 1)) * cpx + (bid >> 3);

    const float* __restrict__ A1 = ws + WS_A1;
    const float* __restrict__ C1 = ws + WS_C1;
    const float* __restrict__ C2 = ws + WS_C2;
    const float* __restrict__ C3 = ws + WS_C3;
    const short* __restrict__ W2f = (const short*)(ws + WS_BF);
    const short* __restrict__ W3f = W2f + 64 * 64;

    for (int pt = 0; pt < PIXT; ++pt) {
        const int pbase = swz * PIXB + pt * 128;

        // ---- Layer 1: 3 -> 64 fp32, fused straight into MFMA A-fragments ----
        // a[mt][ks][j] = relu(W1fold . x + C1) at pixel (w*32+mt*16+lanelo),
        // channel (ks*32+quad*8+j). No LDS, no barrier.
        bf16x8 a[2][2];
        {
            const int p0 = pbase + w * 32 + lanelo;        // mt=0 pixel
            const float x00 = x[p0];
            const float x01 = x[p0 + NPK];
            const float x02 = x[p0 + 2 * NPK];
            const float x10 = x[p0 + 16];                  // mt=1 pixel
            const float x11 = x[p0 + 16 + NPK];
            const float x12 = x[p0 + 16 + 2 * NPK];
#pragma unroll
            for (int ks = 0; ks < 2; ++ks)
#pragma unroll
                for (int j = 0; j < 8; ++j) {
                    const int ch = ks * 32 + quad * 8 + j;
                    const float wa = A1[ch * 3 + 0];
                    const float wb = A1[ch * 3 + 1];
                    const float wc = A1[ch * 3 + 2];
                    const float cc = C1[ch];
                    const float y0 = fmaf(wa, x00, fmaf(wb, x01, fmaf(wc, x02, cc)));
                    const float y1 = fmaf(wa, x10, fmaf(wb, x11, fmaf(wc, x12, cc)));
                    a[0][ks][j] = f2bf(fmaxf(y0, 0.0f));
                    a[1][ks][j] = f2bf(fmaxf(y1, 0.0f));
                }
        }

        // ---- Layer 2: 2 m-tiles x 4 n-tiles, K=64; A-frags already in regs ----
        // h2 rows [32w, 32w+32) are private to this wave: no __syncthreads,
        // and cross-pt reuse is ordered by in-wave lgkmcnt.
#pragma unroll
        for (int nt = 0; nt < 4; ++nt) {
            bf16x8 b0 = *(const bf16x8*)&W2f[((nt * 2 + 0) * 64 + lane) * 8];
            bf16x8 b1 = *(const bf16x8*)&W2f[((nt * 2 + 1) * 64 + lane) * 8];
            const float bias = C2[nt * 16 + lanelo];
#pragma unroll
            for (int mt = 0; mt < 2; ++mt) {
                f32x4 acc = {0.f, 0.f, 0.f, 0.f};
                acc = __builtin_amdgcn_mfma_f32_16x16x32_bf16(a[mt][0], b0, acc, 0, 0, 0);
                acc = __builtin_amdgcn_mfma_f32_16x16x32_bf16(a[mt][1], b1, acc, 0, 0, 0);
#pragma unroll
                for (int r = 0; r < 4; ++r)
                    h2[(w * 32 + mt * 16 + quad * 4 + r) * 72 + nt * 16 + lanelo] =
                        f2bf(fmaxf(acc[r] + bias, 0.0f));
            }
        }

        // ---- Layer 3: 2 m-tiles x 8 n-tiles, K=64; fused epilogue ----
        {
            bf16x8 a2[2][2];
#pragma unroll
            for (int mt = 0; mt < 2; ++mt)
#pragma unroll
                for (int ks = 0; ks < 2; ++ks)
                    a2[mt][ks] = *(const bf16x8*)&h2[(w * 32 + mt * 16 + lanelo) * 72 + ks * 32 + quad * 8];
            f32x4 v4[2];
            v4[0] = *(const f32x4*)&valid[pbase + w * 32 + quad * 4];
            v4[1] = *(const f32x4*)&valid[pbase + w * 32 + 16 + quad * 4];
#pragma unroll
            for (int nt = 0; nt < 8; ++nt) {
                bf16x8 b0 = *(const bf16x8*)&W3f[((nt * 2 + 0) * 64 + lane) * 8];
                bf16x8 b1 = *(const bf16x8*)&W3f[((nt * 2 + 1) * 64 + lane) * 8];
                const float bias = C3[nt * 16 + lanelo];
                const long chbase = (long)(nt * 16 + lanelo) * NPK;
#pragma unroll
                for (int mt = 0; mt < 2; ++mt) {
                    f32x4 acc = {0.f, 0.f, 0.f, 0.f};
                    acc = __builtin_amdgcn_mfma_f32_16x16x32_bf16(a2[mt][0], b0, acc, 0, 0, 0);
                    acc = __builtin_amdgcn_mfma_f32_16x16x32_bf16(a2[mt][1], b1, acc, 0, 0, 0);
                    f32x4 o;
#pragma unroll
                    for (int r = 0; r < 4; ++r)
                        o[r] = fmaxf(acc[r] + bias, 0.0f) * v4[mt][r];
                    *(f32x4*)&out[chbase + pbase + w * 32 + mt * 16 + quad * 4] = o;
                }
            }
        }
    }
}

extern "C" void kernel_launch(void* const* d_in, const int* in_sizes, int n_in,
                              void* d_out, int out_size, void* d_ws, size_t ws_size,
                              hipStream_t stream) {
    const float* x     = (const float*)d_in[0];
    const float* valid = (const float*)d_in[1];

    const float* W1 = (const float*)d_in[2];
    const float* b1 = (const float*)d_in[3];
    const float* g1 = (const float*)d_in[4];
    const float* be1 = (const float*)d_in[5];
    const float* m1 = (const float*)d_in[6];
    const float* v1 = (const float*)d_in[7];

    const float* W2 = (const float*)d_in[8];
    const float* b2 = (const float*)d_in[9];
    const float* g2 = (const float*)d_in[10];
    const float* be2 = (const float*)d_in[11];
    const float* m2 = (const float*)d_in[12];
    const float* v2 = (const float*)d_in[13];

    const float* W3 = (const float*)d_in[14];
    const float* b3 = (const float*)d_in[15];
    const float* g3 = (const float*)d_in[16];
    const float* be3 = (const float*)d_in[17];
    const float* m3 = (const float*)d_in[18];
    const float* v3 = (const float*)d_in[19];

    float* ws  = (float*)d_ws;
    float* out = (float*)d_out;

    prep_kernel<<<16, 256, 0, stream>>>(W1, b1, g1, be1, m1, v1,
                                        W2, b2, g2, be2, m2, v2,
                                        W3, b3, g3, be3, m3, v3, ws);

    pointnet_mfma<<<NPK / PIXB, 256, 0, stream>>>(x, valid, ws, out);
}